// Round 2
// 965.112 us; speedup vs baseline: 1.2804x; 1.2804x over previous
//
#include <hip/hip_runtime.h>
#include <stdint.h>

typedef __attribute__((ext_vector_type(8))) __bf16 bf16x8;
typedef __attribute__((ext_vector_type(4))) float f32x4;

union frag_u { uint4 q; unsigned short s[8]; bf16x8 v; };

__device__ __forceinline__ float b2f(unsigned short u) {
    union { float f; unsigned int u; } x; x.u = ((unsigned int)u) << 16; return x.f;
}
__device__ __forceinline__ unsigned short f2b(float f) {
    union { float f; unsigned int u; } x; x.f = f;
    unsigned int r = x.u + 0x7fffu + ((x.u >> 16) & 1u);
    return (unsigned short)(r >> 16);
}

// C = A @ B, fp32 I/O, bf16 MFMA internal, fp32 acc.
// 256 thr = 4 waves; block tile 128x128, BK=32; wave tile 64x64.
// AMODE 0: A fp32 row-major stride K (converted to bf16 during LDS staging)
// AMODE 1: A bf16 (unsigned short) row-major stride K
// CMODE 0: fp32 C[row*N + col]
// CMODE 1: fp32 C[((row>>11)*4 + (col>>7))*262144 + (row&2047)*128 + (col&127)]
//          ((b,kv,s,128) layout for K/V projections; grid covers 4096 rows)
// CMODE 2: split QG (N=4096, per-batch 2048 rows): hh=col>>8, dd=col&255;
//          dd<128 -> bf16 C [row*2048 + hh*128 + dd]       (query half)
//          else   -> bf16 C2[row*2048 + hh*128 + dd-128]   (gate half)
// KVF 1:   blockIdx.z==1 swaps in (B2, C2v) — fuses the wk/wv launches.
template<int AMODE, int CMODE, int KVF>
__global__ __launch_bounds__(256) void gemm_k(
    const void* __restrict__ Av, const float* __restrict__ B, const float* __restrict__ B2,
    void* __restrict__ Cv, void* __restrict__ C2v, int N, int K)
{
    __shared__ __align__(16) unsigned short Al[128 * 40];
    const float* Bp = B;
    void* Cp = Cv;
    if (KVF && blockIdx.z) { Bp = B2; Cp = C2v; }
    const int tid = threadIdx.x;
    const int w = tid >> 6, l = tid & 63, quad = l >> 4, l16 = l & 15;
    const int wm = (w >> 1) * 64, wn = (w & 1) * 64;
    const int m0 = blockIdx.x * 128, n0 = blockIdx.y * 128;
    f32x4 acc[4][4] = {};
    for (int k0 = 0; k0 < K; k0 += 32) {
        __syncthreads();
#pragma unroll
        for (int i = 0; i < 2; ++i) {
            int chunk = tid + i * 256;
            int row = chunk >> 2, ko = (chunk & 3) * 8;
            if (AMODE == 0) {
                const float* src = (const float*)Av + (size_t)(m0 + row) * K + k0 + ko;
                float4 f0 = *(const float4*)src;
                float4 f1 = *(const float4*)(src + 4);
                unsigned short t[8] = { f2b(f0.x), f2b(f0.y), f2b(f0.z), f2b(f0.w),
                                        f2b(f1.x), f2b(f1.y), f2b(f1.z), f2b(f1.w) };
                *(uint4*)(Al + row * 40 + ko) = *(const uint4*)t;
            } else {
                const unsigned short* src = (const unsigned short*)Av + (size_t)(m0 + row) * K + k0 + ko;
                *(uint4*)(Al + row * 40 + ko) = *(const uint4*)src;
            }
        }
        __syncthreads();
        frag_u af[4];
#pragma unroll
        for (int mt = 0; mt < 4; ++mt)
            af[mt].q = *(const uint4*)(Al + (wm + mt * 16 + l16) * 40 + quad * 8);
#pragma unroll
        for (int nt = 0; nt < 4; ++nt) {
            frag_u bf_;
            const float* bp = Bp + (size_t)(k0 + quad * 8) * N + (n0 + wn + nt * 16 + l16);
#pragma unroll
            for (int j = 0; j < 8; ++j) bf_.s[j] = f2b(bp[(size_t)j * N]);
#pragma unroll
            for (int mt = 0; mt < 4; ++mt)
                acc[mt][nt] = __builtin_amdgcn_mfma_f32_16x16x32_bf16(af[mt].v, bf_.v, acc[mt][nt], 0, 0, 0);
        }
    }
#pragma unroll
    for (int mt = 0; mt < 4; ++mt)
#pragma unroll
        for (int nt = 0; nt < 4; ++nt)
#pragma unroll
            for (int r = 0; r < 4; ++r) {
                int row = m0 + wm + mt * 16 + quad * 4 + r;
                int col = n0 + wn + nt * 16 + l16;
                float vacc = acc[mt][nt][r];
                if (CMODE == 0) {
                    ((float*)Cp)[(size_t)row * N + col] = vacc;
                } else if (CMODE == 1) {
                    ((float*)Cp)[(size_t)((row >> 11) * 4 + (col >> 7)) * 262144
                                 + (size_t)(row & 2047) * 128 + (col & 127)] = vacc;
                } else {
                    int hh = col >> 8, dd = col & 255;
                    unsigned short v = f2b(vacc);
                    if (dd < 128) ((unsigned short*)Cp )[(size_t)row * 2048 + hh * 128 + dd]         = v;
                    else          ((unsigned short*)C2v)[(size_t)row * 2048 + hh * 128 + (dd - 128)] = v;
                }
            }
}

// In-place fp32 RMSNorm + RoPE on KEY (b,kv,s,128). One wave per (b,kv,s).
// Also writes a bf16 copy of the normed+roped K rows to Kb16 (same layout).
__global__ __launch_bounds__(256) void knorm_rope(
    float* __restrict__ Kp, unsigned short* __restrict__ Kb16,
    const float* __restrict__ nw,
    const float* __restrict__ cosb, const float* __restrict__ sinb)
{
    const int tid = threadIdx.x, w = tid >> 6, l = tid & 63;
    const int s = blockIdx.x * 4 + w, kv = blockIdx.y, b = blockIdx.z;
    float* row = Kp + (size_t)((b * 4 + kv) * 2048 + s) * 128;
    float x0 = row[l], x1 = row[l + 64];
    float ss = x0 * x0 + x1 * x1;
#pragma unroll
    for (int m = 1; m < 64; m <<= 1) ss += __shfl_xor(ss, m, 64);
    float r = rsqrtf(ss * (1.0f / 128.0f) + 1e-6f);
    float y0 = x0 * r * nw[l];
    float y1 = x1 * r * nw[l + 64];
    float p = __shfl_xor(y0, 32, 64);
    float c  = cosb[(size_t)(b * 2048 + s) * 64 + l];
    float si = sinb[(size_t)(b * 2048 + s) * 64 + l];
    float yr = y0 * c + (l < 32 ? -p : p) * si;
    row[l] = yr;
    row[l + 64] = y1;
    unsigned short* kb = Kb16 + (size_t)((b * 4 + kv) * 2048 + s) * 128;
    kb[l]      = f2b(yr);
    kb[l + 64] = f2b(y1);
}

// Convert VAL fp32 (b,kv,s,128) -> bf16 V^T (b,kv,128,2048) via LDS transpose.
// Grid (32 s-tiles, 8 bk), 256 thr. Tile = 64 s x 128 d.
__global__ __launch_bounds__(256) void vconv(
    const float* __restrict__ V, unsigned short* __restrict__ Vt)
{
    __shared__ unsigned short T[128 * 65];
    const int tid = threadIdx.x;
    const int s0 = blockIdx.x * 64;
    const int bk = blockIdx.y;
    const float* src = V + (size_t)bk * 262144 + (size_t)s0 * 128;
#pragma unroll
    for (int i = 0; i < 8; ++i) {
        int idx = tid + i * 256;
        int row = idx >> 5, c4 = (idx & 31) * 4;
        float4 f = *(const float4*)(src + (size_t)row * 128 + c4);
        T[(c4 + 0) * 65 + row] = f2b(f.x);
        T[(c4 + 1) * 65 + row] = f2b(f.y);
        T[(c4 + 2) * 65 + row] = f2b(f.z);
        T[(c4 + 3) * 65 + row] = f2b(f.w);
    }
    __syncthreads();
    unsigned short* dst = Vt + (size_t)bk * 262144 + s0;
#pragma unroll
    for (int i = 0; i < 4; ++i) {
        int idx = tid + i * 256;
        int d = idx >> 3, sc = (idx & 7) * 8;
        unsigned short o8[8];
#pragma unroll
        for (int j = 0; j < 8; ++j) o8[j] = T[d * 65 + sc + j];
        *(uint4*)(dst + (size_t)d * 2048 + sc) = *(const uint4*)o8;
    }
}

// Flash-style causal GQA attention, BOTH batches (blockIdx.z). One wave per
// (h, 16 q-rows). Q/gate bf16 from the QG GEMM; K bf16 rows (post norm+rope);
// V bf16 transposed [d][s]. Fused Q RMSNorm + RoPE. Gated-O bf16 out.
__global__ __launch_bounds__(256) void attn(
    const unsigned short* __restrict__ Qall, const unsigned short* __restrict__ K16,
    const unsigned short* __restrict__ V16, unsigned short* __restrict__ Oall,
    const float* __restrict__ cosall, const float* __restrict__ sinall,
    const float* __restrict__ qnw)
{
    __shared__ __align__(16) unsigned short Pb[4][16 * 40];
    __shared__ __align__(16) float Ab[4][16];
    __shared__ __align__(16) unsigned short Ol[4][16 * 136];
    const int tid = threadIdx.x, w = tid >> 6, l = tid & 63, quad = l >> 4, l16 = l & 15;
    const int bb = blockIdx.z;
    // reversed qt: heavy (high-qt) blocks first -> smaller occupancy tail
    const int qt = (31 - blockIdx.x) * 4 + w, h = blockIdx.y, kv = h >> 2;
    const unsigned short* Qb = Qall + (size_t)bb * 8388608;
    const unsigned short* Gb = Qb + 4194304;
    unsigned short* Ob = Oall + (size_t)bb * 4194304;
    const float* cosb_ = cosall + (size_t)bb * 131072;
    const float* sinb_ = sinall + (size_t)bb * 131072;
    const unsigned short* Kb = K16 + (size_t)(bb * 4 + kv) * 262144;
    const unsigned short* Vb = V16 + (size_t)(bb * 4 + kv) * 262144;
    const float SCALE = 0.08838834764831845f;
    const float NEG = -30000.0f;

    // ---- fused Q RMSNorm + RoPE ----
    const int srow = qt * 16 + l16;
    const unsigned short* qrow = Qb + (size_t)srow * 2048 + h * 128;
    frag_u qraw[4];
#pragma unroll
    for (int kk = 0; kk < 4; ++kk) qraw[kk].q = *(const uint4*)(qrow + kk * 32 + quad * 8);
    float qv[4][8];
    float ss = 0.f;
#pragma unroll
    for (int kk = 0; kk < 4; ++kk)
#pragma unroll
        for (int j = 0; j < 8; ++j) { qv[kk][j] = b2f(qraw[kk].s[j]); ss += qv[kk][j] * qv[kk][j]; }
    ss += __shfl_xor(ss, 16, 64);
    ss += __shfl_xor(ss, 32, 64);
    const float rn = rsqrtf(ss * (1.0f / 128.0f) + 1e-6f);
#pragma unroll
    for (int kk = 0; kk < 4; ++kk)
#pragma unroll
        for (int j = 0; j < 8; ++j) qv[kk][j] *= rn * qnw[kk * 32 + quad * 8 + j];
    const float* csrow = cosb_ + (size_t)srow * 64;
    const float* sirow = sinb_ + (size_t)srow * 64;
#pragma unroll
    for (int j = 0; j < 8; ++j) {
        float a0 = qv[0][j], a1 = qv[1][j];
        float c0 = csrow[quad * 8 + j],      s0 = sirow[quad * 8 + j];
        float c1 = csrow[32 + quad * 8 + j], s1 = sirow[32 + quad * 8 + j];
        qv[0][j] = a0 * c0 - a1 * s0;
        qv[1][j] = a1 * c1 + a0 * s1;
    }
    frag_u qf[4];
#pragma unroll
    for (int kk = 0; kk < 4; ++kk)
#pragma unroll
        for (int j = 0; j < 8; ++j) qf[kk].s[j] = f2b(qv[kk][j]);

    // ---- flash loop ----
    f32x4 O[8] = {};
    float M[4], L[4];
#pragma unroll
    for (int r = 0; r < 4; ++r) { M[r] = NEG; L[r] = 0.f; }
    const int qr_base = qt * 16 + quad * 4;
    const int ntiles = (qt * 16 + 16 + 31) >> 5;

    for (int kt = 0; kt < ntiles; ++kt) {
        const int kbase = kt * 32;
        f32x4 sc0 = {}, sc1 = {};
        const unsigned short* k0p = Kb + (size_t)(kbase + l16) * 128 + quad * 8;
#pragma unroll
        for (int kk = 0; kk < 4; ++kk) {
            frag_u kf0, kf1;
            kf0.q = *(const uint4*)(k0p + kk * 32);
            kf1.q = *(const uint4*)(k0p + 2048 + kk * 32);
            sc0 = __builtin_amdgcn_mfma_f32_16x16x32_bf16(qf[kk].v, kf0.v, sc0, 0, 0, 0);
            sc1 = __builtin_amdgcn_mfma_f32_16x16x32_bf16(qf[kk].v, kf1.v, sc1, 0, 0, 0);
        }
        float p0[4], p1[4], alpha[4];
#pragma unroll
        for (int r = 0; r < 4; ++r) {
            float s0 = sc0[r] * SCALE, s1 = sc1[r] * SCALE;
            if (kbase + l16 > qr_base + r)      s0 = NEG;
            if (kbase + 16 + l16 > qr_base + r) s1 = NEG;
            float m = fmaxf(s0, s1);
            m = fmaxf(m, __shfl_xor(m, 1, 64));
            m = fmaxf(m, __shfl_xor(m, 2, 64));
            m = fmaxf(m, __shfl_xor(m, 4, 64));
            m = fmaxf(m, __shfl_xor(m, 8, 64));
            float mn = fmaxf(M[r], m);
            alpha[r] = __expf(M[r] - mn);
            p0[r] = __expf(s0 - mn);
            p1[r] = __expf(s1 - mn);
            float ls = p0[r] + p1[r];
            ls += __shfl_xor(ls, 1, 64);
            ls += __shfl_xor(ls, 2, 64);
            ls += __shfl_xor(ls, 4, 64);
            ls += __shfl_xor(ls, 8, 64);
            L[r] = L[r] * alpha[r] + ls;
            M[r] = mn;
        }
        if (l16 == 0) {
#pragma unroll
            for (int r = 0; r < 4; ++r) Ab[w][quad * 4 + r] = alpha[r];
        }
#pragma unroll
        for (int r = 0; r < 4; ++r) {
            Pb[w][(quad * 4 + r) * 40 + l16]      = f2b(p0[r]);
            Pb[w][(quad * 4 + r) * 40 + 16 + l16] = f2b(p1[r]);
        }
        float ao = Ab[w][l16];
#pragma unroll
        for (int dt = 0; dt < 8; ++dt) {
            O[dt][0] *= ao; O[dt][1] *= ao; O[dt][2] *= ao; O[dt][3] *= ao;
        }
        frag_u pf;
        pf.q = *(const uint4*)(Pb[w] + l16 * 40 + quad * 8);
        const unsigned short* vp = Vb + (size_t)l16 * 2048 + kbase + quad * 8;
#pragma unroll
        for (int dt = 0; dt < 8; ++dt) {
            frag_u vf;
            vf.q = *(const uint4*)(vp + (size_t)dt * 32768);
            O[dt] = __builtin_amdgcn_mfma_f32_16x16x32_bf16(vf.v, pf.v, O[dt], 0, 0, 0);
        }
    }
    if (l16 == 0) {
#pragma unroll
        for (int r = 0; r < 4; ++r) Ab[w][quad * 4 + r] = L[r];
    }
    float rl = 1.0f / Ab[w][l16];
#pragma unroll
    for (int dt = 0; dt < 8; ++dt) {
        unsigned int u0 = (unsigned int)f2b(O[dt][0] * rl) | ((unsigned int)f2b(O[dt][1] * rl) << 16);
        unsigned int u1 = (unsigned int)f2b(O[dt][2] * rl) | ((unsigned int)f2b(O[dt][3] * rl) << 16);
        uint2 u; u.x = u0; u.y = u1;
        *(uint2*)(Ol[w] + l16 * 136 + dt * 16 + quad * 4) = u;
    }
#pragma unroll
    for (int i = 0; i < 4; ++i) {
        int c2 = l + i * 64;
        int row = c2 >> 4, off = (c2 & 15) * 8;
        uint4 v = *(const uint4*)(Ol[w] + row * 136 + off);
        const unsigned short* vs = (const unsigned short*)&v;
        size_t rb = (size_t)(qt * 16 + row) * 2048 + h * 128 + off;
        uint4 g4 = *(const uint4*)(Gb + rb);
        const unsigned short* gs = (const unsigned short*)&g4;
        unsigned short o8[8];
#pragma unroll
        for (int j = 0; j < 8; ++j) {
            float o = b2f(vs[j]), g = b2f(gs[j]);
            o8[j] = f2b(o / (1.0f + __expf(-g)));
        }
        *(uint4*)(Ob + rb) = *(const uint4*)o8;
    }
}

extern "C" void kernel_launch(void* const* d_in, const int* in_sizes, int n_in,
                              void* d_out, int out_size, void* d_ws, size_t ws_size,
                              hipStream_t stream)
{
    const float* x    = (const float*)d_in[0];   // (2,2048,2048)
    const float* cosb = (const float*)d_in[1];   // (2,2048,64)
    const float* sinb = (const float*)d_in[2];
    const float* wq   = (const float*)d_in[3];   // (2048,4096)
    const float* wk   = (const float*)d_in[4];   // (2048,512)
    const float* wv   = (const float*)d_in[5];
    const float* wo   = (const float*)d_in[6];   // (2048,2048)
    const float* qnw  = (const float*)d_in[7];   // (128,)
    const float* knw  = (const float*)d_in[8];

    float* out = (float*)d_out;                  // 12582912 floats
    float* KEY = out + 8388608;                  // (2,4,2048,128) fp32
    float* VAL = out + 10485760;                 // (2,4,2048,128) fp32

    // Scratch (zero d_ws usage):
    //  - d_out's "out" region (floats [0, 8388608)) viewed as shorts holds
    //    Q_A[0,4M) | gate_A[4M,8M) | Q_B[8M,12M) | gate_B[12M,16M) bf16.
    //  - x's buffer (restored by the harness before every launch), shorts view
    //    (16,777,216 shorts total):
    //      [0,        8388608)  gated-O both batches (x batch-0 floats, dead
    //                           after the QG GEMMs)
    //      [8388608, 10485760)  bf16 K (b,kv,s,128)   — x batch-1 floats, dead
    //      [10485760,12582912)  bf16 V^T (b,kv,128,2048)
    //    knorm_rope/vconv run after ALL GEMMs that read x (stream order).
    unsigned short* outs = (unsigned short*)d_out;
    unsigned short* xg   = (unsigned short*)d_in[0];
    unsigned short* K16  = xg + 8388608;
    unsigned short* V16  = xg + 10485760;

    // K and V projections fused in one launch (z picks wk/wv), fp32 into d_out.
    gemm_k<0,1,1><<<dim3(32, 4, 2), 256, 0, stream>>>(x, wk, wv, KEY, VAL, 512, 2048);

    // QG projections (bf16 Q/gate into d_out scratch) — both batches.
    gemm_k<0,2,0><<<dim3(16, 32), 256, 0, stream>>>(x, wq, nullptr,
                                                    outs, outs + 4194304, 4096, 2048);
    gemm_k<0,2,0><<<dim3(16, 32), 256, 0, stream>>>(x + 4194304, wq, nullptr,
                                                    outs + 8388608, outs + 12582912, 4096, 2048);

    // x is now fully consumed: K norm+rope (fp32 in-place + bf16 copy), V^T bf16.
    knorm_rope<<<dim3(512, 4, 2), 256, 0, stream>>>(KEY, K16, knw, cosb, sinb);
    vconv<<<dim3(32, 8), 256, 0, stream>>>(VAL, V16);

    // Single attention launch, both batches (z), gated-O bf16 into xg.
    attn<<<dim3(32, 16, 2), 256, 0, stream>>>(outs, K16, V16, xg, cosb, sinb, qnw);

    // Final projection: out(fp32) = gated-O(bf16) @ wo(fp32).
    gemm_k<1,0,0><<<dim3(32, 16), 256, 0, stream>>>(xg, wo, nullptr, out, nullptr, 2048, 2048);
}